// Round 7
// baseline (541.041 us; speedup 1.0000x reference)
//
#include <hip/hip_runtime.h>
#include <cstddef>

#define Bv 4
#define Nv 24
#define NTv 16
#define Tv 64
#define NP 25
#define NEGF (-1e30f)

// ---------------- workspace layout (floats) ----------------
// betaA layout: [B][25 l][25 r][24 head][16 sym]  (head-major for coalesced lane reads)
#define BETAA_OFF 0         // [B][25][25][24 head][16 sym]            960000
#define BETAU_OFF 960000    // [B][25][25][64 sym]                     160000
#define RNT_OFF   1120000   // [B][2 d][24 h][16 A][16 sL][16 sR]      786432
#define T0_OFF    1906432   // [B][24 h][24 p][16 sL][16 A]            589824
#define T1_OFF    2496256   // [B][24 h][24 p][16 sR][16 A]            589824
#define T0L_OFF   3086080   // [B][24 h][16 sR][16 A]                  24576
#define T1R_OFF   3110656   // [B][24 h][16 sL][16 A]                  24576
#define D0_OFF    3135232   // [B][24 l][16 A]                         1536
#define D1_OFF    3136768   // [B][24 l][16 A]                         1536
#define EU_OFF    3138304   // [B][24 p][48 j]  exp(unary terminal)    4608
#define PROG_OFF  3142912   // [B][32] int progress flags              128
#define WS_NEED   3143040

// publish one float to the device coherence point (LLC) without any L2 sweep:
// plain store keeps writer-L2 hot; relaxed agent RMW-swap lands the value at the
// coherence point (RMWs always execute there -- no buffer_wbl2 needed).
__device__ __forceinline__ void publish(float* p, float v) {
  *p = v;
  (void)__hip_atomic_exchange(p, v, __ATOMIC_RELAXED, __HIP_MEMORY_SCOPE_AGENT);
}

// ---- init: width-1 betau + exp(unary) table + progress flags ----
__global__ void init_kernel(const float* __restrict__ unary, float* __restrict__ betau,
                            float* __restrict__ Eu, int* __restrict__ prog) {
  int t = blockIdx.x * blockDim.x + threadIdx.x;
  if (t < Bv * 32) prog[t] = 0;
  if (t >= Bv * Nv * 48) return;
  int i = t % 48, kk = (t / 48) % Nv, b = t / (48 * Nv);
  float u = unary[(size_t)(b * Nv + kk) * Tv + 16 + i];
  betau[((size_t)(b * NP + kk) * NP + (kk + 1)) * Tv + 16 + i] = u;
  Eu[(size_t)(b * Nv + kk) * 48 + i] = __expf(u);
}

// ---- fused prep: block per (b,A,h); coalesced 32KB rule read; all precontractions ----
__global__ __launch_bounds__(256) void prep_kernel(
    const float* __restrict__ rule, const float* __restrict__ Eu,
    float* __restrict__ RNT, float* __restrict__ T0, float* __restrict__ T1,
    float* __restrict__ T0L, float* __restrict__ T1R,
    float* __restrict__ D0, float* __restrict__ D1) {
  const int h = blockIdx.x, A = blockIdx.y, b = blockIdx.z;
  const int t = threadIdx.x;  // 256
  __shared__ float er0[64 * 65];  // exp(rule[..,sL,sR,0]), padded rows
  __shared__ float er1[64 * 65];
  __shared__ float E[24 * 48];
  __shared__ float red[256];

  for (int i = t; i < 24 * 48; i += 256) E[i] = Eu[(size_t)b * (24 * 48) + i];
  const float* rb = rule + (size_t)((b * NTv + A) * Nv + h) * 8192;
#pragma unroll
  for (int i = 0; i < 8; ++i) {
    int lin = i * 1024 + t * 4;  // = sL*128 + sR*2 + d
    float4 v = *(const float4*)(rb + lin);
    int sL = lin >> 7, rem = (lin & 127) >> 1;
    er0[sL * 65 + rem] = __expf(v.x);
    er1[sL * 65 + rem] = __expf(v.y);
    er0[sL * 65 + rem + 1] = __expf(v.z);
    er1[sL * 65 + rem + 1] = __expf(v.w);
  }
  __syncthreads();
  // RNT (A-major layout): coalesced 1KB store per d
  {
    float* dst0 = RNT + (((size_t)(b * 2 + 0) * Nv + h) * NTv + A) * 256;
    float* dst1 = RNT + (((size_t)(b * 2 + 1) * Nv + h) * NTv + A) * 256;
    dst0[t] = er0[(t >> 4) * 65 + (t & 15)];
    dst1[t] = er1[(t >> 4) * 65 + (t & 15)];
  }
  // T0[b,h,p,sL,A] = sum_j E[p][j]*er0[sL][16+j]
  for (int o = t; o < 384; o += 256) {
    int p = o >> 4, sL = o & 15;
    const float* Ep = E + p * 48;
    const float* r0 = er0 + sL * 65 + 16;
    float acc = 0.f;
#pragma unroll 8
    for (int j = 0; j < 48; ++j) acc += Ep[j] * r0[j];
    T0[(((size_t)(b * Nv + h) * Nv + p) * NTv + sL) * NTv + A] = acc;
  }
  // T1[b,h,p,sR,A] = sum_i E[p][i]*er1[16+i][sR]
  for (int o = t; o < 384; o += 256) {
    int p = o >> 4, sR = o & 15;
    const float* Ep = E + p * 48;
    float acc = 0.f;
#pragma unroll 8
    for (int i = 0; i < 48; ++i) acc += Ep[i] * er1[(16 + i) * 65 + sR];
    T1[(((size_t)(b * Nv + h) * Nv + p) * NTv + sR) * NTv + A] = acc;
  }
  if (t < 16) {  // T0L[b,h,sR,A] = sum_i er0[16+i][sR]
    float acc = 0.f;
    for (int i = 0; i < 48; ++i) acc += er0[(16 + i) * 65 + t];
    T0L[((size_t)(b * Nv + h) * NTv + t) * NTv + A] = acc;
  } else if (t < 32) {  // T1R[b,h,sL,A] = sum_j er1[sL][16+j]
    int sL = t - 16;
    float acc = 0.f;
    for (int j = 0; j < 48; ++j) acc += er1[sL * 65 + 16 + j];
    T1R[((size_t)(b * Nv + h) * NTv + sL) * NTv + A] = acc;
  }
  // D0[b,l=h,A] = sum_{i,j} E[h+1][j]*er0[16+i][16+j];  D1[b,l=h-1,A] likewise
  float acc0 = 0.f, acc1 = 0.f;
  const int hp = (h + 1 < 24) ? h + 1 : 0, hm = (h >= 1) ? h - 1 : 0;
  for (int e = t; e < 2304; e += 256) {
    int i = e / 48, j = e % 48;
    float r0 = er0[(16 + i) * 65 + 16 + j];
    float r1 = er1[(16 + i) * 65 + 16 + j];
    acc0 += E[hp * 48 + j] * r0;
    acc1 += E[hm * 48 + i] * r1;
  }
  red[t] = acc0;
  __syncthreads();
  if (t < 64) {
    float s = red[t] + red[t + 64] + red[t + 128] + red[t + 192];
#pragma unroll
    for (int off = 32; off; off >>= 1) s += __shfl_xor(s, off, 64);
    if (t == 0 && h <= 22) D0[((size_t)b * Nv + h) * NTv + A] = s;
  }
  __syncthreads();
  red[t] = acc1;
  __syncthreads();
  if (t < 64) {
    float s = red[t] + red[t + 64] + red[t + 128] + red[t + 192];
#pragma unroll
    for (int off = 32; off; off >>= 1) s += __shfl_xor(s, off, 64);
    if (t == 0 && h >= 1) D1[((size_t)b * Nv + (h - 1)) * NTv + A] = s;
  }
}

__device__ __forceinline__ float max16(float v) {
  v = fmaxf(v, __shfl_xor(v, 8, 16));
  v = fmaxf(v, __shfl_xor(v, 4, 16));
  v = fmaxf(v, __shfl_xor(v, 2, 16));
  v = fmaxf(v, __shfl_xor(v, 1, 16));
  return v;
}

__device__ __forceinline__ void edge_dot(float v0, float v1, float v2, float v3,
                                         const float* Tb, float& sh, float& S) {
  float mx = fmaxf(fmaxf(v0, v1), fmaxf(v2, v3));
  mx = fmaxf(mx, __shfl_xor(mx, 1, 64));
  mx = fmaxf(mx, __shfl_xor(mx, 2, 64));
  float dot = __expf(v0 - mx) * Tb[0] + __expf(v1 - mx) * Tb[16] +
              __expf(v2 - mx) * Tb[32] + __expf(v3 - mx) * Tb[48];
  dot += __shfl_xor(dot, 1, 64);
  dot += __shfl_xor(dot, 2, 64);
  sh = mx;
  S = dot;
}

#define MAXI 21  // max interior splits per direction

// ---- persistent width kernel: wave-specialized A(W+1) || B(W) pipeline,
//      sweep-free publication (no buffer_wbl2 on the critical chain) ----
__global__ __launch_bounds__(768) void width_all_kernel(
    const float* __restrict__ unary, float* __restrict__ betaA, float* __restrict__ betau,
    const float* __restrict__ RNT, const float* __restrict__ T0, const float* __restrict__ T1,
    const float* __restrict__ T0L, const float* __restrict__ T1R,
    const float* __restrict__ D0, const float* __restrict__ D1,
    const float* __restrict__ root, float* __restrict__ out, int* __restrict__ prog) {
  const int l = blockIdx.x, b = blockIdx.y;
  const int tid = threadIdx.x;
  const int Wmax = Nv - l;
  int* progb = prog + b * 32;

  __shared__ float U0[2][24 * 256], U1[2][24 * 256];  // double-buffered
  __shared__ float sG0[2][24], sG1[2][24];
  __shared__ float cLs[16 * 25];          // rolling copy of chart(l, r-1): [sym][hh]
  __shared__ float bu[25 * 16];           // own betau(l,l+w)[NT], w>=2
  __shared__ float pM[2 * 24 * 16], pS[2 * 24 * 16];
  __shared__ float sTmp[16 * 24];
  __shared__ float sFin[16];

  // pre-loop: A(2) is trivially empty -> zero buffer 0
  for (int i = tid; i < 24 * 256; i += 768) { U0[0][i] = 0.f; U1[0][i] = 0.f; }
  if (tid < 24) { sG0[0][tid] = NEGF; sG1[0][tid] = NEGF; }

  for (int W = 2; W <= Wmax; ++W) {
    __syncthreads();  // top: previous epilogue (betaA row, bu, cLs) visible
    const int r = l + W;
    const int cur = W & 1;

    if (tid >= 384) {
      // ---------------- A-waves: Phase A for width W+1 ----------------
      if (W < Wmax) {
        if (W >= 3) {
          while (__hip_atomic_load(&progb[l + 2], __ATOMIC_RELAXED,
                                   __HIP_MEMORY_SCOPE_AGENT) < W - 1)
            __builtin_amdgcn_s_sleep(1);
        }
        const int gg = (tid - 384) >> 5;  // 0..11
        const int k = tid & 31;           // 384 % 64 == 0 -> lane-aligned groups
        const int W1 = W + 1, r1 = l + W1;
        const int nxt = W1 & 1;
#pragma unroll
        for (int hrep = 0; hrep < 2; ++hrep) {
          const int g = gg + 12 * hrep;
          if (g < W1) {
            const int hcol = l + g;
            float av1[MAXI], av0[MAXI];
            // d1 interior: m in [l+2, min(l+g, r1-2)]
            int e1 = min(l + g, r1 - 2);
            int cnt1 = e1 - (l + 2) + 1; if (cnt1 < 0) cnt1 = 0;
            if (k < 16) {
#pragma unroll
              for (int i = 0; i < MAXI; ++i)
                if (i < cnt1) av1[i] = bu[(2 + i) * 16 + k];
            } else {
              const size_t base = (size_t)(b * NP) * NP * 384 + (size_t)r1 * 384 +
                                  (size_t)hcol * 16 + (k - 16);
#pragma unroll
              for (int i = 0; i < MAXI; ++i)
                if (i < cnt1) av1[i] = betaA[base + (size_t)(l + 2 + i) * (NP * 384)];
            }
            // d0 interior: m in [max(l+g+1, l+2), r1-2]
            int m0 = max(l + g + 1, l + 2), e0 = r1 - 2;
            int cnt0 = e0 - m0 + 1; if (cnt0 < 0) cnt0 = 0;
            if (k < 16) {
              const size_t base = ((size_t)(b * NP + l) * NP) * 384 + (size_t)hcol * 16 + k;
#pragma unroll
              for (int i = 0; i < MAXI; ++i)
                if (i < cnt0) av0[i] = betaA[base + (size_t)(m0 + i) * 384];
            } else {
              const size_t base = (size_t)(b * NP) * NP * Tv + (size_t)r1 * Tv + (k - 16);
#pragma unroll
              for (int i = 0; i < MAXI; ++i)
                if (i < cnt0) av0[i] = betau[base + (size_t)(m0 + i) * (NP * Tv)];
            }
            float mx1 = NEGF, mx0 = NEGF;
#pragma unroll
            for (int i = 0; i < MAXI; ++i) {
              if (i < cnt1) mx1 = fmaxf(mx1, av1[i]);
              if (i < cnt0) mx0 = fmaxf(mx0, av0[i]);
            }
            float o1 = max16(mx1), o0 = max16(mx0);
            float t1 = __shfl_xor(o1, 16, 32), t0 = __shfl_xor(o0, 16, 32);
            float G1v = o1 + t1, G0v = o0 + t0;
            float U0r[8], U1r[8];
#pragma unroll
            for (int j = 0; j < 8; ++j) { U0r[j] = 0.f; U1r[j] = 0.f; }
#pragma unroll
            for (int i = 0; i < MAXI; ++i) {
              if (i < cnt1) {
                float e = __expf(av1[i] - o1);
                float eR = __shfl(e, 16 + (k & 15), 32);
#pragma unroll
                for (int j = 0; j < 8; ++j)
                  U1r[j] += __shfl(e, 2 * j + (k >> 4), 32) * eR;
              }
              if (i < cnt0) {
                float e = __expf(av0[i] - o0);
                float eR = __shfl(e, 16 + (k & 15), 32);
#pragma unroll
                for (int j = 0; j < 8; ++j)
                  U0r[j] += __shfl(e, 2 * j + (k >> 4), 32) * eR;
              }
            }
#pragma unroll
            for (int j = 0; j < 8; ++j) {
              U0[nxt][g * 256 + k + 32 * j] = U0r[j];
              U1[nxt][g * 256 + k + 32 * j] = U1r[j];
            }
            if (k == 0) { sG0[nxt][g] = G0v; sG1[nxt][g] = G1v; }
          }
        }
      }
    } else {
      // ---------------- B-waves: Phase B for width W ----------------
      if (W >= 3) {
        while (__hip_atomic_load(&progb[l + 1], __ATOMIC_RELAXED,
                                 __HIP_MEMORY_SCOPE_AGENT) < W - 1)
          __builtin_amdgcn_s_sleep(1);
      }
      const int w6 = tid >> 6, lane = tid & 63;
      const int A = lane >> 2, q = lane & 3;
      const float* buW1 = bu + (W - 1) * 16;  // betau(l, r-1)[NT]
      for (int p = w6; p < 2 * W; p += 6) {
        const int hh = p >> 1, d = p & 1;
        const int h = l + hh;
        const float* Urow = (d ? U1[cur] : U0[cur]) + hh * 256 + 4 * q;
        const float* Rb = RNT + (((size_t)(b * 2 + d) * Nv + h) * NTv + A) * 256 + 4 * q;
        float a0 = 0.f, a1 = 0.f, a2 = 0.f, a3 = 0.f;
#pragma unroll
        for (int sL = 0; sL < 16; ++sL) {
          float4 u = *(const float4*)(Urow + sL * 16);
          float4 rv = *(const float4*)(Rb + sL * 16);
          a0 += u.x * rv.x; a1 += u.y * rv.y; a2 += u.z * rv.z; a3 += u.w * rv.w;
        }
        float acc = (a0 + a1) + (a2 + a3);
        acc += __shfl_xor(acc, 1, 64);
        acc += __shfl_xor(acc, 2, 64);
        float Mi = d ? sG1[cur][hh] : sG0[cur][hh];
        float sh2 = NEGF, S2 = 0.f, sh3 = NEGF, S3 = 0.f;
        if (W >= 3) {
          if (d == 0) {
            if (hh < W - 1) {  // split m=r-1: chart(l,r-1) x terminal via T0 (LDS rolling)
              const float* Tb = T0 + (((size_t)(b * Nv + h) * Nv + (r - 1)) * NTv + 4 * q) * NTv + A;
              edge_dot(cLs[(4 * q + 0) * 25 + hh], cLs[(4 * q + 1) * 25 + hh],
                       cLs[(4 * q + 2) * 25 + hh], cLs[(4 * q + 3) * 25 + hh], Tb, sh2, S2);
            }
            if (hh == 0) {     // split m=l+1: terminal x betau(l+1,r) via T0L (direct)
              const float* Tb = T0L + ((size_t)(b * Nv + l) * NTv + 4 * q) * NTv + A;
              float4 u4 = *(const float4*)(betau +
                  ((size_t)(b * NP + (l + 1)) * NP + r) * Tv + 4 * q);
              edge_dot(u4.x, u4.y, u4.z, u4.w, Tb, sh3, S3);
            }
          } else {
            if (hh >= 1) {     // split m=l+1: terminal x chart(l+1,r) via T1 (direct)
              const float* Tb = T1 + (((size_t)(b * Nv + h) * Nv + l) * NTv + 4 * q) * NTv + A;
              float4 e4 = *(const float4*)(betaA +
                  ((size_t)(b * NP + (l + 1)) * NP + r) * 384 + (size_t)(l + hh) * 16 + 4 * q);
              edge_dot(e4.x, e4.y, e4.z, e4.w, Tb, sh2, S2);
            }
            if (hh == W - 1) { // split m=r-1: betau(l,r-1) x terminal via T1R (LDS)
              const float* Tb = T1R + ((size_t)(b * Nv + (r - 1)) * NTv + 4 * q) * NTv + A;
              edge_dot(buW1[4 * q + 0], buW1[4 * q + 1], buW1[4 * q + 2], buW1[4 * q + 3],
                       Tb, sh3, S3);
            }
          }
        } else {  // W == 2
          if (d == 0 && hh == 0) { sh2 = 0.f; S2 = D0[((size_t)b * Nv + l) * NTv + A]; }
          if (d == 1 && hh == 1) { sh2 = 0.f; S2 = D1[((size_t)b * Nv + l) * NTv + A]; }
        }
        float Mf = fmaxf(Mi, fmaxf(sh2, sh3));
        float Sf = acc * __expf(Mi - Mf) + S2 * __expf(sh2 - Mf) + S3 * __expf(sh3 - Mf);
        if (q == 0) {
          pM[(d * 24 + hh) * 16 + A] = Mf;
          pS[(d * 24 + hh) * 16 + A] = Sf;
        }
      }
    }
    __syncthreads();  // bar1: pM/pS (and next-U) complete

    // combine dirs, publish betaA ([head][sym]), rolling cLs, prep betau input
    if (tid < 384) {
      int A2 = tid & 15, hh = tid >> 4;
      if (hh < W) {
        float M0 = pM[(0 * 24 + hh) * 16 + A2], S0 = pS[(0 * 24 + hh) * 16 + A2];
        float M1 = pM[(1 * 24 + hh) * 16 + A2], S1 = pS[(1 * 24 + hh) * 16 + A2];
        float nm = fmaxf(M0, M1);
        float s = S0 * __expf(M0 - nm) + S1 * __expf(M1 - nm);
        float val = nm + __logf(s);
        publish(&betaA[((size_t)(b * NP + l) * NP + r) * 384 + (l + hh) * 16 + A2], val);
        cLs[A2 * 25 + hh] = val;  // rolling copy for next step's T0-edge
        sTmp[A2 * 24 + hh] = val + unary[(size_t)(b * Nv + (l + hh)) * Tv + A2];
      }
    }
    __syncthreads();  // bar2: sTmp complete; betaA publishes drained (implicit vmcnt(0))
    if (tid < 16) {
      float mx = NEGF;
      for (int x = 0; x < W; ++x) mx = fmaxf(mx, sTmp[tid * 24 + x]);
      float s = 0.f;
      for (int x = 0; x < W; ++x) s += __expf(sTmp[tid * 24 + x] - mx);
      float val = mx + __logf(s);
      publish(&betau[((size_t)(b * NP + l) * NP + r) * Tv + tid], val);
      bu[W * 16 + tid] = val;
      if (W == Nv) sFin[tid] = val;  // only l==0 reaches W==Nv
    }
    // flag: wave 0's betau publishes drained by explicit vmcnt(0); then a relaxed
    // RMW-swap (executes at coherence point) -- no buffer_wbl2 anywhere.
    if (tid == 0) {
      asm volatile("s_waitcnt vmcnt(0)" ::: "memory");
      (void)__hip_atomic_exchange(&progb[l], W, __ATOMIC_RELAXED, __HIP_MEMORY_SCOPE_AGENT);
    }
  }

  // ---- final: block (0,b) computes out[b] from its own W==Nv results ----
  if (l == 0) {
    __syncthreads();
    if (tid == 0) {
      float vals[NTv];
      float mx = NEGF;
#pragma unroll
      for (int A = 0; A < NTv; ++A) {
        float v = sFin[A] + root[b * NTv + A];
        vals[A] = v;
        mx = fmaxf(mx, v);
      }
      float s = 0.f;
#pragma unroll
      for (int A = 0; A < NTv; ++A) s += __expf(vals[A] - mx);
      out[b] = mx + __logf(s);
    }
  }
}

// ---- fallback width kernel (direct rule reads, self-consistent layout) ----
__global__ __launch_bounds__(768) void width_kernel_fb(
    const float* __restrict__ unary, const float* __restrict__ rule,
    float* __restrict__ betaA, float* __restrict__ betau, int W) {
  const int l = blockIdx.x, b = blockIdx.y;
  const int r = l + W;
  const int tid = threadIdx.x;
  const int sub = tid & 1;
  const int pid = tid >> 1;
  const int A = pid & 15;
  const int hh = pid >> 4;
  const int h = l + hh;
  const bool act = (hh < W);
  const int sA = tid & 15, sH = tid >> 4;

  __shared__ float sER0[48], sEL1[48];
  __shared__ float sCL0[16 * 24], sCR1[16 * 24];
  __shared__ float sMaxL0[24], sMaxR1[24];
  __shared__ float sShR0, sShL1;
  __shared__ float sTmp[16 * 24];

  float runM = NEGF, runS = 0.f;
  for (int m = l + 1; m < r; ++m) {
    const int wl = m - l, wr = r - m;
    if (tid < 64) {
      const int n = (wr == 1) ? 48 : 16, s0 = (wr == 1) ? 16 : 0;
      float v = (tid < n) ? betau[(size_t)((b * NP + m) * NP + r) * Tv + s0 + tid] : NEGF;
      float mx = v;
#pragma unroll
      for (int off = 32; off; off >>= 1) mx = fmaxf(mx, __shfl_xor(mx, off, 64));
      if (tid == 0) sShR0 = mx;
      if (tid < n) sER0[tid] = v - mx;
    } else if (tid < 128) {
      const int j = tid - 64;
      const int n = (wl == 1) ? 48 : 16, s0 = (wl == 1) ? 16 : 0;
      float v = (j < n) ? betau[(size_t)((b * NP + l) * NP + m) * Tv + s0 + j] : NEGF;
      float mx = v;
#pragma unroll
      for (int off = 32; off; off >>= 1) mx = fmaxf(mx, __shfl_xor(mx, off, 64));
      if (j == 0) sShL1 = mx;
      if (j < n) sEL1[j] = v - mx;
    }
    if (tid < 384) {
      if (wl > 1 && sH < wl) {
        float v = betaA[(size_t)((b * NP + l) * NP + m) * 384 + sA * Nv + (l + sH)];
        float mx = v;
#pragma unroll
        for (int off = 8; off; off >>= 1) mx = fmaxf(mx, __shfl_xor(mx, off, 16));
        if (sA == 0) sMaxL0[sH] = mx;
        sCL0[sA * Nv + sH] = v - mx;
      }
      if (wr > 1 && sH >= wl && sH < W) {
        float v = betaA[(size_t)((b * NP + m) * NP + r) * 384 + sA * Nv + (l + sH)];
        float mx = v;
#pragma unroll
        for (int off = 8; off; off >>= 1) mx = fmaxf(mx, __shfl_xor(mx, off, 16));
        if (sA == 0) sMaxR1[sH] = mx;
        sCR1[sA * Nv + sH] = v - mx;
      }
    }
    __syncthreads();
    if (act) {
      if (hh < wl && (wl > 1 || hh == 0)) {
        const int nL = (wl == 1) ? 48 : 16, sL0 = (wl == 1) ? 16 : 0;
        const int nR = (wr == 1) ? 48 : 16, sR0 = (wr == 1) ? 16 : 0;
        const float shift = ((wl == 1) ? 0.f : sMaxL0[hh]) + sShR0;
        float part = 0.f;
        const float* rb = rule + (size_t)(((b * NTv + A) * Nv + h) * Tv) * Tv * 2;
        for (int i = sub; i < nL; i += 2) {
          const float cl = (wl == 1) ? 0.f : sCL0[i * Nv + hh];
          const float* rp = rb + (size_t)(sL0 + i) * Tv * 2 + sR0 * 2;
#pragma unroll 8
          for (int j = 0; j < nR; ++j) part += __expf(cl + sER0[j] + rp[j * 2]);
        }
        float nm = fmaxf(runM, shift);
        runS = runS * __expf(runM - nm) + part * __expf(shift - nm);
        runM = nm;
      }
      if (hh >= wl && (wr > 1 || hh == W - 1)) {
        const int nL = (wl == 1) ? 48 : 16, sL0 = (wl == 1) ? 16 : 0;
        const int nR = (wr == 1) ? 48 : 16, sR0 = (wr == 1) ? 16 : 0;
        const float shift = sShL1 + ((wr == 1) ? 0.f : sMaxR1[hh]);
        float part = 0.f;
        const float* rb = rule + (size_t)(((b * NTv + A) * Nv + h) * Tv) * Tv * 2 + 1;
        for (int i = sub; i < nL; i += 2) {
          const float el = sEL1[i];
          const float* rp = rb + (size_t)(sL0 + i) * Tv * 2 + sR0 * 2;
#pragma unroll 8
          for (int j = 0; j < nR; ++j) {
            const float cr = (wr == 1) ? 0.f : sCR1[j * Nv + hh];
            part += __expf(el + cr + rp[j * 2]);
          }
        }
        float nm = fmaxf(runM, shift);
        runS = runS * __expf(runM - nm) + part * __expf(shift - nm);
        runM = nm;
      }
    }
    __syncthreads();
  }
  if (act) {
    float om = __shfl_xor(runM, 1, 64);
    float os = __shfl_xor(runS, 1, 64);
    float nm = fmaxf(runM, om);
    float s = runS * __expf(runM - nm) + os * __expf(om - nm);
    if (sub == 0) {
      float val = nm + __logf(s);
      betaA[(size_t)((b * NP + l) * NP + r) * 384 + A * Nv + h] = val;
      sTmp[A * Nv + hh] = val + unary[(b * Nv + h) * Tv + A];
    }
  }
  __syncthreads();
  if (tid < 16) {
    float mx = NEGF;
    for (int x = 0; x < W; ++x) mx = fmaxf(mx, sTmp[tid * Nv + x]);
    float s = 0.f;
    for (int x = 0; x < W; ++x) s += __expf(sTmp[tid * Nv + x] - mx);
    betau[(size_t)((b * NP + l) * NP + r) * Tv + tid] = mx + __logf(s);
  }
}

__global__ void final_kernel(const float* __restrict__ betau, const float* __restrict__ root,
                             float* __restrict__ out) {
  int b = threadIdx.x;
  if (b < Bv) {
    float vals[NTv];
    float mx = NEGF;
#pragma unroll
    for (int A = 0; A < NTv; ++A) {
      float v = betau[(size_t)((b * NP + 0) * NP + Nv) * Tv + A] + root[b * NTv + A];
      vals[A] = v;
      mx = fmaxf(mx, v);
    }
    float s = 0.f;
#pragma unroll
    for (int A = 0; A < NTv; ++A) s += __expf(vals[A] - mx);
    out[b] = mx + __logf(s);
  }
}

extern "C" void kernel_launch(void* const* d_in, const int* in_sizes, int n_in,
                              void* d_out, int out_size, void* d_ws, size_t ws_size,
                              hipStream_t stream) {
  (void)in_sizes; (void)n_in; (void)out_size;
  const float* unary = (const float*)d_in[0];
  const float* rule  = (const float*)d_in[1];
  const float* root  = (const float*)d_in[2];
  float* out = (float*)d_out;
  float* ws = (float*)d_ws;
  float* betaA = ws + BETAA_OFF;
  float* betau = ws + BETAU_OFF;
  const bool fast = ws_size >= (size_t)WS_NEED * sizeof(float);

  if (fast) {
    float* RNT = ws + RNT_OFF;
    float* T0  = ws + T0_OFF;
    float* T1  = ws + T1_OFF;
    float* T0L = ws + T0L_OFF;
    float* T1R = ws + T1R_OFF;
    float* D0  = ws + D0_OFF;
    float* D1  = ws + D1_OFF;
    float* Eu  = ws + EU_OFF;
    int* prog  = (int*)(ws + PROG_OFF);
    init_kernel<<<(Bv * Nv * 48 + 255) / 256, 256, 0, stream>>>(unary, betau, Eu, prog);
    prep_kernel<<<dim3(24, 16, 4), 256, 0, stream>>>(rule, Eu, RNT, T0, T1, T0L, T1R, D0, D1);
    void* args[] = {(void*)&unary, (void*)&betaA, (void*)&betau, (void*)&RNT,
                    (void*)&T0, (void*)&T1, (void*)&T0L, (void*)&T1R,
                    (void*)&D0, (void*)&D1, (void*)&root, (void*)&out, (void*)&prog};
    hipLaunchCooperativeKernel((const void*)width_all_kernel, dim3(Nv - 1, Bv), dim3(768),
                               args, 0, stream);
  } else {
    float* Eu = ws + BETAU_OFF + 160000;  // reuse space past betau for Eu in fallback
    int* prog = (int*)(ws + BETAU_OFF + 160000 + 4608);
    init_kernel<<<(Bv * Nv * 48 + 255) / 256, 256, 0, stream>>>(unary, betau, Eu, prog);
    for (int W = 2; W <= Nv; ++W) {
      dim3 grid(Nv - W + 1, Bv);
      width_kernel_fb<<<grid, 768, 0, stream>>>(unary, rule, betaA, betau, W);
    }
    final_kernel<<<1, 64, 0, stream>>>(betau, root, out);
  }
}

// Round 8
// 491.106 us; speedup vs baseline: 1.1017x; 1.1017x over previous
//
#include <hip/hip_runtime.h>
#include <cstddef>

#define Bv 4
#define Nv 24
#define NTv 16
#define Tv 64
#define NP 25
#define NEGF (-1e30f)

// ---------------- workspace layout (floats) ----------------
// betaA layout: [B][25 l][25 r][24 head][16 sym]  (head-major for coalesced lane reads)
#define BETAA_OFF 0         // [B][25][25][24 head][16 sym]            960000
#define BETAU_OFF 960000    // [B][25][25][64 sym]                     160000
#define RNT_OFF   1120000   // [B][2 d][24 h][16 A][16 sL][16 sR]      786432
#define T0_OFF    1906432   // [B][24 h][24 p][16 sL][16 A]            589824
#define T1_OFF    2496256   // [B][24 h][24 p][16 sR][16 A]            589824
#define T0L_OFF   3086080   // [B][24 h][16 sR][16 A]                  24576
#define T1R_OFF   3110656   // [B][24 h][16 sL][16 A]                  24576
#define D0_OFF    3135232   // [B][24 l][16 A]                         1536
#define D1_OFF    3136768   // [B][24 l][16 A]                         1536
#define EU_OFF    3138304   // [B][24 p][48 j]  exp(unary terminal)    4608
#define PROG_OFF  3142912   // [B][32] int per-column progress         128
#define WS_NEED   3143040

// publish one float so cross-XCD readers see it: plain store keeps writer-L2
// hot; relaxed agent RMW-swap lands the value at the device coherence point.
// (R7-verified pattern.)
__device__ __forceinline__ void publish(float* p, float v) {
  *p = v;
  (void)__hip_atomic_exchange(p, v, __ATOMIC_RELAXED, __HIP_MEMORY_SCOPE_AGENT);
}

// ---- init: width-1 betau + exp(unary) table + progress flags ----
__global__ void init_kernel(const float* __restrict__ unary, float* __restrict__ betau,
                            float* __restrict__ Eu, int* __restrict__ prog) {
  int t = blockIdx.x * blockDim.x + threadIdx.x;
  if (t < Bv * 32) prog[t] = 0;
  if (t >= Bv * Nv * 48) return;
  int i = t % 48, kk = (t / 48) % Nv, b = t / (48 * Nv);
  float u = unary[(size_t)(b * Nv + kk) * Tv + 16 + i];
  betau[((size_t)(b * NP + kk) * NP + (kk + 1)) * Tv + 16 + i] = u;
  Eu[(size_t)(b * Nv + kk) * 48 + i] = __expf(u);
}

// ---- fused prep: block per (b,A,h); coalesced 32KB rule read; all precontractions ----
__global__ __launch_bounds__(256) void prep_kernel(
    const float* __restrict__ rule, const float* __restrict__ Eu,
    float* __restrict__ RNT, float* __restrict__ T0, float* __restrict__ T1,
    float* __restrict__ T0L, float* __restrict__ T1R,
    float* __restrict__ D0, float* __restrict__ D1) {
  const int h = blockIdx.x, A = blockIdx.y, b = blockIdx.z;
  const int t = threadIdx.x;  // 256
  __shared__ float er0[64 * 65];  // exp(rule[..,sL,sR,0]), padded rows
  __shared__ float er1[64 * 65];
  __shared__ float E[24 * 48];
  __shared__ float red[256];

  for (int i = t; i < 24 * 48; i += 256) E[i] = Eu[(size_t)b * (24 * 48) + i];
  const float* rb = rule + (size_t)((b * NTv + A) * Nv + h) * 8192;
#pragma unroll
  for (int i = 0; i < 8; ++i) {
    int lin = i * 1024 + t * 4;  // = sL*128 + sR*2 + d
    float4 v = *(const float4*)(rb + lin);
    int sL = lin >> 7, rem = (lin & 127) >> 1;
    er0[sL * 65 + rem] = __expf(v.x);
    er1[sL * 65 + rem] = __expf(v.y);
    er0[sL * 65 + rem + 1] = __expf(v.z);
    er1[sL * 65 + rem + 1] = __expf(v.w);
  }
  __syncthreads();
  // RNT (A-major layout): coalesced 1KB store per d
  {
    float* dst0 = RNT + (((size_t)(b * 2 + 0) * Nv + h) * NTv + A) * 256;
    float* dst1 = RNT + (((size_t)(b * 2 + 1) * Nv + h) * NTv + A) * 256;
    dst0[t] = er0[(t >> 4) * 65 + (t & 15)];
    dst1[t] = er1[(t >> 4) * 65 + (t & 15)];
  }
  // T0[b,h,p,sL,A] = sum_j E[p][j]*er0[sL][16+j]
  for (int o = t; o < 384; o += 256) {
    int p = o >> 4, sL = o & 15;
    const float* Ep = E + p * 48;
    const float* r0 = er0 + sL * 65 + 16;
    float acc = 0.f;
#pragma unroll 8
    for (int j = 0; j < 48; ++j) acc += Ep[j] * r0[j];
    T0[(((size_t)(b * Nv + h) * Nv + p) * NTv + sL) * NTv + A] = acc;
  }
  // T1[b,h,p,sR,A] = sum_i E[p][i]*er1[16+i][sR]
  for (int o = t; o < 384; o += 256) {
    int p = o >> 4, sR = o & 15;
    const float* Ep = E + p * 48;
    float acc = 0.f;
#pragma unroll 8
    for (int i = 0; i < 48; ++i) acc += Ep[i] * er1[(16 + i) * 65 + sR];
    T1[(((size_t)(b * Nv + h) * Nv + p) * NTv + sR) * NTv + A] = acc;
  }
  if (t < 16) {  // T0L[b,h,sR,A] = sum_i er0[16+i][sR]
    float acc = 0.f;
    for (int i = 0; i < 48; ++i) acc += er0[(16 + i) * 65 + t];
    T0L[((size_t)(b * Nv + h) * NTv + t) * NTv + A] = acc;
  } else if (t < 32) {  // T1R[b,h,sL,A] = sum_j er1[sL][16+j]
    int sL = t - 16;
    float acc = 0.f;
    for (int j = 0; j < 48; ++j) acc += er1[sL * 65 + 16 + j];
    T1R[((size_t)(b * Nv + h) * NTv + sL) * NTv + A] = acc;
  }
  // D0[b,l=h,A] = sum_{i,j} E[h+1][j]*er0[16+i][16+j];  D1[b,l=h-1,A] likewise
  float acc0 = 0.f, acc1 = 0.f;
  const int hp = (h + 1 < 24) ? h + 1 : 0, hm = (h >= 1) ? h - 1 : 0;
  for (int e = t; e < 2304; e += 256) {
    int i = e / 48, j = e % 48;
    float r0 = er0[(16 + i) * 65 + 16 + j];
    float r1 = er1[(16 + i) * 65 + 16 + j];
    acc0 += E[hp * 48 + j] * r0;
    acc1 += E[hm * 48 + i] * r1;
  }
  red[t] = acc0;
  __syncthreads();
  if (t < 64) {
    float s = red[t] + red[t + 64] + red[t + 128] + red[t + 192];
#pragma unroll
    for (int off = 32; off; off >>= 1) s += __shfl_xor(s, off, 64);
    if (t == 0 && h <= 22) D0[((size_t)b * Nv + h) * NTv + A] = s;
  }
  __syncthreads();
  red[t] = acc1;
  __syncthreads();
  if (t < 64) {
    float s = red[t] + red[t + 64] + red[t + 128] + red[t + 192];
#pragma unroll
    for (int off = 32; off; off >>= 1) s += __shfl_xor(s, off, 64);
    if (t == 0 && h >= 1) D1[((size_t)b * Nv + (h - 1)) * NTv + A] = s;
  }
}

__device__ __forceinline__ float max16(float v) {
  v = fmaxf(v, __shfl_xor(v, 8, 16));
  v = fmaxf(v, __shfl_xor(v, 4, 16));
  v = fmaxf(v, __shfl_xor(v, 2, 16));
  v = fmaxf(v, __shfl_xor(v, 1, 16));
  return v;
}

__device__ __forceinline__ void edge_dot(float v0, float v1, float v2, float v3,
                                         const float* Tb, float& sh, float& S) {
  float mx = fmaxf(fmaxf(v0, v1), fmaxf(v2, v3));
  mx = fmaxf(mx, __shfl_xor(mx, 1, 64));
  mx = fmaxf(mx, __shfl_xor(mx, 2, 64));
  float dot = __expf(v0 - mx) * Tb[0] + __expf(v1 - mx) * Tb[16] +
              __expf(v2 - mx) * Tb[32] + __expf(v3 - mx) * Tb[48];
  dot += __shfl_xor(dot, 1, 64);
  dot += __shfl_xor(dot, 2, 64);
  sh = mx;
  S = dot;
}

#define MAXI 21  // max interior splits per direction

// ---- column-per-block persistent kernel ----
// Block (rr,b) owns column r=rr+2: cells (r-2,r), (r-3,r), ..., (0,r) in order.
// The DP critical chain C(l,r) <- C(l+1,r) is INTRA-block (LDS chartC/buC).
// Cross-block deps are row reads (l,m) from column-blocks m<r with slack r-m
// cells (column m's cells are strictly cheaper), so polls detect instantly in
// steady state. Flags: colFlag[b][m] = #completed cells of column m.
__global__ __launch_bounds__(768) void width_all_kernel(
    const float* __restrict__ unary, float* __restrict__ betaA, float* __restrict__ betau,
    const float* __restrict__ RNT, const float* __restrict__ T0, const float* __restrict__ T1,
    const float* __restrict__ T0L, const float* __restrict__ T1R,
    const float* __restrict__ D0, const float* __restrict__ D1,
    const float* __restrict__ root, float* __restrict__ out, int* __restrict__ colFlag) {
  const int rr = blockIdx.x, b = blockIdx.y;
  const int r = rr + 2;
  const int tid = threadIdx.x;
  int* flagb = colFlag + b * 32;

  __shared__ float chartC[23][384];  // own column cells (l',r): [l'][head*16+sym]
  __shared__ float buC[23][16];      // own column betau NT: [l'][sym]
  __shared__ float U0[24 * 256], U1[24 * 256];
  __shared__ float sG0[24], sG1[24];
  __shared__ float pM[2 * 24 * 16], pS[2 * 24 * 16];
  __shared__ float sTmp[16 * 24];

  for (int i = 0; i <= r - 2; ++i) {
    const int l = r - 2 - i;
    const int W = r - l;  // = i + 2

    if (W >= 3) {
      // poll columns m in [l+2, r-1]: need cell (l,m) done -> flag[m] >= m-l-1
      if (tid < W - 2) {
        const int m = l + 2 + tid;
        while (__hip_atomic_load(&flagb[m], __ATOMIC_RELAXED,
                                 __HIP_MEMORY_SCOPE_AGENT) < m - l - 1)
          __builtin_amdgcn_s_sleep(1);
      }
      __syncthreads();
    }

    // ---- Phase A: batched loads, global-max shift, factored-exp outer product ----
    const int g = tid >> 5;   // head offset 0..23
    const int k = tid & 31;   // group lane
    float U0r[8], U1r[8];
#pragma unroll
    for (int j = 0; j < 8; ++j) { U0r[j] = 0.f; U1r[j] = 0.f; }
    float G0 = NEGF, G1 = NEGF;

    if (g < W) {
      const int hcol = l + g;
      float av1[MAXI], av0[MAXI];
      // d1 splits: m in [l+2, min(l+g, r-2)]  (head in right child)
      int e1 = min(l + g, r - 2);
      int cnt1 = e1 - (l + 2) + 1; if (cnt1 < 0) cnt1 = 0;
      if (k < 16) {  // left betau(l,m)[k]  -- global row read (cross column m)
        const size_t base = ((size_t)(b * NP + l) * NP + (l + 2)) * Tv + k;
#pragma unroll
        for (int ii = 0; ii < MAXI; ++ii)
          if (ii < cnt1) av1[ii] = betau[base + (size_t)ii * Tv];
      } else {       // right chart(m,r)[hcol][k-16]  -- OWN column, LDS
#pragma unroll
        for (int ii = 0; ii < MAXI; ++ii)
          if (ii < cnt1) av1[ii] = chartC[l + 2 + ii][hcol * 16 + (k - 16)];
      }
      // d0 splits: m in [max(l+g+1, l+2), r-2]  (head in left child)
      int m0 = max(l + g + 1, l + 2), e0 = r - 2;
      int cnt0 = e0 - m0 + 1; if (cnt0 < 0) cnt0 = 0;
      if (k < 16) {  // left chart(l,m)[hcol][k]  -- global row read (cross column m)
        const size_t base = ((size_t)(b * NP + l) * NP + m0) * 384 + (size_t)hcol * 16 + k;
#pragma unroll
        for (int ii = 0; ii < MAXI; ++ii)
          if (ii < cnt0) av0[ii] = betaA[base + (size_t)ii * 384];
      } else {       // right betau(m,r)[k-16]  -- OWN column, LDS
#pragma unroll
        for (int ii = 0; ii < MAXI; ++ii)
          if (ii < cnt0) av0[ii] = buC[m0 + ii][k - 16];
      }
      // per-lane maxes over splits
      float mx1 = NEGF, mx0 = NEGF;
#pragma unroll
      for (int ii = 0; ii < MAXI; ++ii) {
        if (ii < cnt1) mx1 = fmaxf(mx1, av1[ii]);
        if (ii < cnt0) mx0 = fmaxf(mx0, av0[ii]);
      }
      float o1 = max16(mx1), o0 = max16(mx0);
      float t1 = __shfl_xor(o1, 16, 32), t0 = __shfl_xor(o0, 16, 32);
      G1 = o1 + t1;
      G0 = o0 + t0;
#pragma unroll
      for (int ii = 0; ii < MAXI; ++ii) {
        if (ii < cnt1) {
          float e = __expf(av1[ii] - o1);
          float eR = __shfl(e, 16 + (k & 15), 32);
#pragma unroll
          for (int j = 0; j < 8; ++j)
            U1r[j] += __shfl(e, 2 * j + (k >> 4), 32) * eR;
        }
        if (ii < cnt0) {
          float e = __expf(av0[ii] - o0);
          float eR = __shfl(e, 16 + (k & 15), 32);
#pragma unroll
          for (int j = 0; j < 8; ++j)
            U0r[j] += __shfl(e, 2 * j + (k >> 4), 32) * eR;
        }
      }
#pragma unroll
      for (int j = 0; j < 8; ++j) {
        U0[g * 256 + k + 32 * j] = U0r[j];
        U1[g * 256 + k + 32 * j] = U1r[j];
      }
      if (k == 0) { sG0[g] = G0; sG1[g] = G1; }
    }
    __syncthreads();

    // ---- Phase B: per (head,dir) contraction; lane = (A, q) ----
    {
      const int w = tid >> 6, lane = tid & 63;
      const int A = lane >> 2, q = lane & 3;
      for (int p = w; p < 2 * W; p += 12) {
        const int hh = p >> 1, d = p & 1;
        const int h = l + hh;
        const float* Urow = (d ? U1 : U0) + hh * 256 + 4 * q;
        const float* Rb = RNT + (((size_t)(b * 2 + d) * Nv + h) * NTv + A) * 256 + 4 * q;
        float a0 = 0.f, a1 = 0.f, a2 = 0.f, a3 = 0.f;
#pragma unroll
        for (int sL = 0; sL < 16; ++sL) {
          float4 u = *(const float4*)(Urow + sL * 16);
          float4 rv = *(const float4*)(Rb + sL * 16);
          a0 += u.x * rv.x; a1 += u.y * rv.y; a2 += u.z * rv.z; a3 += u.w * rv.w;
        }
        float acc = (a0 + a1) + (a2 + a3);
        acc += __shfl_xor(acc, 1, 64);
        acc += __shfl_xor(acc, 2, 64);
        float Mi = d ? sG1[hh] : sG0[hh];
        float sh2 = NEGF, S2 = 0.f, sh3 = NEGF, S3 = 0.f;
        if (W >= 3) {
          if (d == 0) {
            if (hh < W - 1) {  // split m=r-1: chart(l,r-1) x terminal via T0 (global row)
              const float* Tb = T0 + (((size_t)(b * Nv + h) * Nv + (r - 1)) * NTv + 4 * q) * NTv + A;
              float4 e4 = *(const float4*)(betaA +
                  ((size_t)(b * NP + l) * NP + (r - 1)) * 384 + (size_t)h * 16 + 4 * q);
              edge_dot(e4.x, e4.y, e4.z, e4.w, Tb, sh2, S2);
            }
            if (hh == 0) {     // split m=l+1: terminal x betau(l+1,r) via T0L (own, LDS)
              const float* Tb = T0L + ((size_t)(b * Nv + l) * NTv + 4 * q) * NTv + A;
              const float* u4 = &buC[l + 1][4 * q];
              edge_dot(u4[0], u4[1], u4[2], u4[3], Tb, sh3, S3);
            }
          } else {
            if (hh >= 1) {     // split m=l+1: terminal x chart(l+1,r) via T1 (own, LDS)
              const float* Tb = T1 + (((size_t)(b * Nv + h) * Nv + l) * NTv + 4 * q) * NTv + A;
              const float* e4 = &chartC[l + 1][h * 16 + 4 * q];
              edge_dot(e4[0], e4[1], e4[2], e4[3], Tb, sh2, S2);
            }
            if (hh == W - 1) { // split m=r-1: betau(l,r-1) x terminal via T1R (global row)
              const float* Tb = T1R + ((size_t)(b * Nv + (r - 1)) * NTv + 4 * q) * NTv + A;
              float4 u4 = *(const float4*)(betau +
                  ((size_t)(b * NP + l) * NP + (r - 1)) * Tv + 4 * q);
              edge_dot(u4.x, u4.y, u4.z, u4.w, Tb, sh3, S3);
            }
          }
        } else {  // W == 2
          if (d == 0 && hh == 0) { sh2 = 0.f; S2 = D0[((size_t)b * Nv + l) * NTv + A]; }
          if (d == 1 && hh == 1) { sh2 = 0.f; S2 = D1[((size_t)b * Nv + l) * NTv + A]; }
        }
        float Mf = fmaxf(Mi, fmaxf(sh2, sh3));
        float Sf = acc * __expf(Mi - Mf) + S2 * __expf(sh2 - Mf) + S3 * __expf(sh3 - Mf);
        if (q == 0) {
          pM[(d * 24 + hh) * 16 + A] = Mf;
          pS[(d * 24 + hh) * 16 + A] = Sf;
        }
      }
    }
    __syncthreads();

    // combine dirs; publish betaA + fill own chartC; prep betau input
    if (tid < 384) {
      int A2 = tid & 15, hh = tid >> 4;
      if (hh < W) {
        float M0 = pM[(0 * 24 + hh) * 16 + A2], S0 = pS[(0 * 24 + hh) * 16 + A2];
        float M1 = pM[(1 * 24 + hh) * 16 + A2], S1 = pS[(1 * 24 + hh) * 16 + A2];
        float nm = fmaxf(M0, M1);
        float s = S0 * __expf(M0 - nm) + S1 * __expf(M1 - nm);
        float val = nm + __logf(s);
        publish(&betaA[((size_t)(b * NP + l) * NP + r) * 384 + (l + hh) * 16 + A2], val);
        chartC[l][(l + hh) * 16 + A2] = val;
        sTmp[A2 * 24 + hh] = val + unary[(size_t)(b * Nv + (l + hh)) * Tv + A2];
      }
    }
    __syncthreads();  // sTmp ready; betaA publishes drained (implicit vmcnt(0))
    if (tid < 16) {
      float mx = NEGF;
      for (int x = 0; x < W; ++x) mx = fmaxf(mx, sTmp[tid * 24 + x]);
      float s = 0.f;
      for (int x = 0; x < W; ++x) s += __expf(sTmp[tid * 24 + x] - mx);
      float val = mx + __logf(s);
      publish(&betau[((size_t)(b * NP + l) * NP + r) * Tv + tid], val);
      buC[l][tid] = val;
    }
    if (tid == 0) {
      asm volatile("s_waitcnt vmcnt(0)" ::: "memory");  // drain wave0 betau publishes
      (void)__hip_atomic_exchange(&flagb[r], i + 1, __ATOMIC_RELAXED,
                                  __HIP_MEMORY_SCOPE_AGENT);
    }
  }

  // ---- final: column-24 block computes out[b] from its own cell (0,24) ----
  if (rr == 22) {
    __syncthreads();
    if (tid == 0) {
      float vals[NTv];
      float mx = NEGF;
#pragma unroll
      for (int A = 0; A < NTv; ++A) {
        float v = buC[0][A] + root[b * NTv + A];
        vals[A] = v;
        mx = fmaxf(mx, v);
      }
      float s = 0.f;
#pragma unroll
      for (int A = 0; A < NTv; ++A) s += __expf(vals[A] - mx);
      out[b] = mx + __logf(s);
    }
  }
}

// ---- fallback width kernel (direct rule reads, self-consistent layout) ----
__global__ __launch_bounds__(768) void width_kernel_fb(
    const float* __restrict__ unary, const float* __restrict__ rule,
    float* __restrict__ betaA, float* __restrict__ betau, int W) {
  const int l = blockIdx.x, b = blockIdx.y;
  const int r = l + W;
  const int tid = threadIdx.x;
  const int sub = tid & 1;
  const int pid = tid >> 1;
  const int A = pid & 15;
  const int hh = pid >> 4;
  const int h = l + hh;
  const bool act = (hh < W);
  const int sA = tid & 15, sH = tid >> 4;

  __shared__ float sER0[48], sEL1[48];
  __shared__ float sCL0[16 * 24], sCR1[16 * 24];
  __shared__ float sMaxL0[24], sMaxR1[24];
  __shared__ float sShR0, sShL1;
  __shared__ float sTmp[16 * 24];

  float runM = NEGF, runS = 0.f;
  for (int m = l + 1; m < r; ++m) {
    const int wl = m - l, wr = r - m;
    if (tid < 64) {
      const int n = (wr == 1) ? 48 : 16, s0 = (wr == 1) ? 16 : 0;
      float v = (tid < n) ? betau[(size_t)((b * NP + m) * NP + r) * Tv + s0 + tid] : NEGF;
      float mx = v;
#pragma unroll
      for (int off = 32; off; off >>= 1) mx = fmaxf(mx, __shfl_xor(mx, off, 64));
      if (tid == 0) sShR0 = mx;
      if (tid < n) sER0[tid] = v - mx;
    } else if (tid < 128) {
      const int j = tid - 64;
      const int n = (wl == 1) ? 48 : 16, s0 = (wl == 1) ? 16 : 0;
      float v = (j < n) ? betau[(size_t)((b * NP + l) * NP + m) * Tv + s0 + j] : NEGF;
      float mx = v;
#pragma unroll
      for (int off = 32; off; off >>= 1) mx = fmaxf(mx, __shfl_xor(mx, off, 64));
      if (j == 0) sShL1 = mx;
      if (j < n) sEL1[j] = v - mx;
    }
    if (tid < 384) {
      if (wl > 1 && sH < wl) {
        float v = betaA[(size_t)((b * NP + l) * NP + m) * 384 + sA * Nv + (l + sH)];
        float mx = v;
#pragma unroll
        for (int off = 8; off; off >>= 1) mx = fmaxf(mx, __shfl_xor(mx, off, 16));
        if (sA == 0) sMaxL0[sH] = mx;
        sCL0[sA * Nv + sH] = v - mx;
      }
      if (wr > 1 && sH >= wl && sH < W) {
        float v = betaA[(size_t)((b * NP + m) * NP + r) * 384 + sA * Nv + (l + sH)];
        float mx = v;
#pragma unroll
        for (int off = 8; off; off >>= 1) mx = fmaxf(mx, __shfl_xor(mx, off, 16));
        if (sA == 0) sMaxR1[sH] = mx;
        sCR1[sA * Nv + sH] = v - mx;
      }
    }
    __syncthreads();
    if (act) {
      if (hh < wl && (wl > 1 || hh == 0)) {
        const int nL = (wl == 1) ? 48 : 16, sL0 = (wl == 1) ? 16 : 0;
        const int nR = (wr == 1) ? 48 : 16, sR0 = (wr == 1) ? 16 : 0;
        const float shift = ((wl == 1) ? 0.f : sMaxL0[hh]) + sShR0;
        float part = 0.f;
        const float* rb = rule + (size_t)(((b * NTv + A) * Nv + h) * Tv) * Tv * 2;
        for (int i = sub; i < nL; i += 2) {
          const float cl = (wl == 1) ? 0.f : sCL0[i * Nv + hh];
          const float* rp = rb + (size_t)(sL0 + i) * Tv * 2 + sR0 * 2;
#pragma unroll 8
          for (int j = 0; j < nR; ++j) part += __expf(cl + sER0[j] + rp[j * 2]);
        }
        float nm = fmaxf(runM, shift);
        runS = runS * __expf(runM - nm) + part * __expf(shift - nm);
        runM = nm;
      }
      if (hh >= wl && (wr > 1 || hh == W - 1)) {
        const int nL = (wl == 1) ? 48 : 16, sL0 = (wl == 1) ? 16 : 0;
        const int nR = (wr == 1) ? 48 : 16, sR0 = (wr == 1) ? 16 : 0;
        const float shift = sShL1 + ((wr == 1) ? 0.f : sMaxR1[hh]);
        float part = 0.f;
        const float* rb = rule + (size_t)(((b * NTv + A) * Nv + h) * Tv) * Tv * 2 + 1;
        for (int i = sub; i < nL; i += 2) {
          const float el = sEL1[i];
          const float* rp = rb + (size_t)(sL0 + i) * Tv * 2 + sR0 * 2;
#pragma unroll 8
          for (int j = 0; j < nR; ++j) {
            const float cr = (wr == 1) ? 0.f : sCR1[j * Nv + hh];
            part += __expf(el + cr + rp[j * 2]);
          }
        }
        float nm = fmaxf(runM, shift);
        runS = runS * __expf(runM - nm) + part * __expf(shift - nm);
        runM = nm;
      }
    }
    __syncthreads();
  }
  if (act) {
    float om = __shfl_xor(runM, 1, 64);
    float os = __shfl_xor(runS, 1, 64);
    float nm = fmaxf(runM, om);
    float s = runS * __expf(runM - nm) + os * __expf(om - nm);
    if (sub == 0) {
      float val = nm + __logf(s);
      betaA[(size_t)((b * NP + l) * NP + r) * 384 + A * Nv + h] = val;
      sTmp[A * Nv + hh] = val + unary[(b * Nv + h) * Tv + A];
    }
  }
  __syncthreads();
  if (tid < 16) {
    float mx = NEGF;
    for (int x = 0; x < W; ++x) mx = fmaxf(mx, sTmp[tid * Nv + x]);
    float s = 0.f;
    for (int x = 0; x < W; ++x) s += __expf(sTmp[tid * Nv + x] - mx);
    betau[(size_t)((b * NP + l) * NP + r) * Tv + tid] = mx + __logf(s);
  }
}

__global__ void final_kernel(const float* __restrict__ betau, const float* __restrict__ root,
                             float* __restrict__ out) {
  int b = threadIdx.x;
  if (b < Bv) {
    float vals[NTv];
    float mx = NEGF;
#pragma unroll
    for (int A = 0; A < NTv; ++A) {
      float v = betau[(size_t)((b * NP + 0) * NP + Nv) * Tv + A] + root[b * NTv + A];
      vals[A] = v;
      mx = fmaxf(mx, v);
    }
    float s = 0.f;
#pragma unroll
    for (int A = 0; A < NTv; ++A) s += __expf(vals[A] - mx);
    out[b] = mx + __logf(s);
  }
}

extern "C" void kernel_launch(void* const* d_in, const int* in_sizes, int n_in,
                              void* d_out, int out_size, void* d_ws, size_t ws_size,
                              hipStream_t stream) {
  (void)in_sizes; (void)n_in; (void)out_size;
  const float* unary = (const float*)d_in[0];
  const float* rule  = (const float*)d_in[1];
  const float* root  = (const float*)d_in[2];
  float* out = (float*)d_out;
  float* ws = (float*)d_ws;
  float* betaA = ws + BETAA_OFF;
  float* betau = ws + BETAU_OFF;
  const bool fast = ws_size >= (size_t)WS_NEED * sizeof(float);

  if (fast) {
    float* RNT = ws + RNT_OFF;
    float* T0  = ws + T0_OFF;
    float* T1  = ws + T1_OFF;
    float* T0L = ws + T0L_OFF;
    float* T1R = ws + T1R_OFF;
    float* D0  = ws + D0_OFF;
    float* D1  = ws + D1_OFF;
    float* Eu  = ws + EU_OFF;
    int* colFlag = (int*)(ws + PROG_OFF);
    init_kernel<<<(Bv * Nv * 48 + 255) / 256, 256, 0, stream>>>(unary, betau, Eu, colFlag);
    prep_kernel<<<dim3(24, 16, 4), 256, 0, stream>>>(rule, Eu, RNT, T0, T1, T0L, T1R, D0, D1);
    void* args[] = {(void*)&unary, (void*)&betaA, (void*)&betau, (void*)&RNT,
                    (void*)&T0, (void*)&T1, (void*)&T0L, (void*)&T1R,
                    (void*)&D0, (void*)&D1, (void*)&root, (void*)&out, (void*)&colFlag};
    hipLaunchCooperativeKernel((const void*)width_all_kernel, dim3(Nv - 1, Bv), dim3(768),
                               args, 0, stream);
  } else {
    float* Eu = ws + BETAU_OFF + 160000;  // reuse space past betau for Eu in fallback
    int* prog = (int*)(ws + BETAU_OFF + 160000 + 4608);
    init_kernel<<<(Bv * Nv * 48 + 255) / 256, 256, 0, stream>>>(unary, betau, Eu, prog);
    for (int W = 2; W <= Nv; ++W) {
      dim3 grid(Nv - W + 1, Bv);
      width_kernel_fb<<<grid, 768, 0, stream>>>(unary, rule, betaA, betau, W);
    }
    final_kernel<<<1, 64, 0, stream>>>(betau, root, out);
  }
}